// Round 1
// baseline (66.540 us; speedup 1.0000x reference)
//
#include <hip/hip_runtime.h>
#include <stdint.h>

#define N_TOK 4096
#define D_IN  64
#define NF    32
#define NH    4
#define OUTW  (NH * NF)        // 128
#define CHUNK 128
#define NCH   (N_TOK / CHUNK)  // 32
#define BT    16
#define NT    8

typedef float        f32x4  __attribute__((ext_vector_type(4)));
typedef unsigned int uint4v __attribute__((ext_vector_type(4)));
typedef __bf16       bf16x8 __attribute__((ext_vector_type(8)));
typedef short        short8 __attribute__((ext_vector_type(8)));

union Frag { uint4v u; bf16x8 v; };

static __device__ __forceinline__ unsigned short f2bf_rne(float x) {
  unsigned u = __float_as_uint(x);
  u += 0x7fffu + ((u >> 16) & 1u);
  return (unsigned short)(u >> 16);
}
static __device__ __forceinline__ float bf2f(unsigned short x) {
  return __uint_as_float(((unsigned)x) << 16);
}

// ---------------- Kernel 1: WG^T (bf16) and E_dst = exp(WG . a_dst) ----------------
__global__ __launch_bounds__(128) void prep_kernel(
    const float* __restrict__ G, const float* __restrict__ W,
    const float* __restrict__ bias, const float* __restrict__ a_dst,
    unsigned short* __restrict__ ED, unsigned short* __restrict__ WGT) {
  __shared__ float gs[NT * D_IN];  // 8 G rows, 2 KB
  const int tid = threadIdx.x;
  const int n0  = blockIdx.x * NT;
  {
    const float4* src = (const float4*)(G + (size_t)n0 * D_IN);
    float4* dst = (float4*)gs;
    dst[tid] = src[tid];  // 128 thr x 16B = 2 KB
  }
  __syncthreads();
  const int h = tid >> 5, f = tid & 31;
  float acc[NT];
  const float bb = bias[h * NF + f];
#pragma unroll
  for (int k = 0; k < NT; ++k) acc[k] = bb;
#pragma unroll
  for (int i = 0; i < D_IN; ++i) {
    const float wv = W[(h * D_IN + i) * NF + f];
#pragma unroll
    for (int k = 0; k < NT; ++k) acc[k] = fmaf(gs[k * D_IN + i], wv, acc[k]);
  }
  union { uint4 u4; unsigned short us[8]; } pk;
#pragma unroll
  for (int k = 0; k < NT; ++k) pk.us[k] = f2bf_rne(acc[k]);
  *(uint4*)&WGT[(size_t)(h * NF + f) * N_TOK + n0] = pk.u4;

  const float ad = a_dst[h * NF + f];
  float ev[NT];
#pragma unroll
  for (int k = 0; k < NT; ++k) {
    float s = acc[k] * ad;
    s += __shfl_xor(s, 1);  s += __shfl_xor(s, 2);  s += __shfl_xor(s, 4);
    s += __shfl_xor(s, 8);  s += __shfl_xor(s, 16);
    ev[k] = __expf(s);
  }
  if (f == 0) {
    union { uint4 u4; unsigned short us[8]; } pe;
#pragma unroll
    for (int k = 0; k < NT; ++k) pe.us[k] = f2bf_rne(ev[k]);
    *(uint4*)&ED[(size_t)h * N_TOK + n0] = pe.u4;
  }
}

// ---------------- Kernel 2: fused masked softmax + PV via MFMA ----------------
// 256 blocks x 512 thr. Block: 16 b-rows. Wave w: head = w>>1, f-half = (w&1)*16.
// p[b,n,h] = exp(-A[b,n]) * E_dst[n,h]; out = relu( (P @ WG) / rowsum(P) ).
__global__ __launch_bounds__(512) void attn_kernel(
    const float* __restrict__ A, const unsigned short* __restrict__ ED,
    const unsigned short* __restrict__ WGT, float* __restrict__ out) {
  __shared__ float ea[4][BT * CHUNK];        // 4 ring buffers, 8 KB each (swizzled)
  __shared__ unsigned short eds[NH * N_TOK]; // E_dst bf16, 32 KB

  const int tid  = threadIdx.x;
  const int lane = tid & 63;
  const int wv   = tid >> 6;
  const int h    = wv >> 1;
  const int f0   = (wv & 1) * 16;
  const int b0   = blockIdx.x * BT;

  { // ED -> LDS (32 KB)
    const uint4* src = (const uint4*)ED;
    uint4* dst = (uint4*)eds;
#pragma unroll
    for (int i = 0; i < 4; ++i) dst[tid + i * 512] = src[tid + i * 512];
  }

  // Staging: LDS granule s=tid holds A[row = s>>5][4*g .. 4*g+3], g = (s&31)^(row&7)
  // (source-swizzled so swizzled-LDS content + linear global_load_lds dest agree).
  const int srow = tid >> 5;
  const int sg   = (tid & 31) ^ (srow & 7);
  const float* abase = A + (size_t)(b0 + srow) * N_TOK + sg * 4;

  // MFMA fragment addressing: A-frag row = lane&15, k = (lane>>4)*8 + j
  const int rowm = lane & 15;
  const int koff = (lane >> 4) * 8;
  const int rsw  = (rowm & 7) << 4;  // XOR bank swizzle (16B granules)
  const unsigned short* wbase =
      WGT + (size_t)(h * NF + f0 + rowm) * N_TOK + koff;

  f32x4 acc = {0.f, 0.f, 0.f, 0.f};
  float dsum = 0.f;
  Frag fa0, fa1, fa2, fa3, fb0, fb1, fb2, fb3;

#define STAGE(bi, cc)                                                              \
  __builtin_amdgcn_global_load_lds(                                               \
      (const __attribute__((address_space(1))) void*)(abase + (size_t)(cc) * CHUNK), \
      (__attribute__((address_space(3))) void*)(&ea[bi][tid * 4]), 16, 0, 0)

#define LOADB(fr, cc, ss)                                                          \
  asm volatile("global_load_dwordx4 %0, %1, off"                                  \
               : "=v"(fr.u)                                                        \
               : "v"(wbase + (size_t)(cc) * CHUNK + (ss) * 32)                     \
               : "memory")

#define EXPP(bi) do {                                                              \
    float* p_ = &ea[bi][tid * 4];                                                  \
    f32x4 v_ = *(const f32x4*)p_;                                                  \
    v_[0] = __expf(-v_[0]); v_[1] = __expf(-v_[1]);                                \
    v_[2] = __expf(-v_[2]); v_[3] = __expf(-v_[3]);                                \
    *(f32x4*)p_ = v_;                                                              \
  } while (0)

#define MSTEP(fr, cc, ss) do {                                                     \
    const char* eb_ = (const char*)(&ea[(cc) & 3][0]);                             \
    const int nl_ = (ss) * 32 + koff;                                              \
    const int by_ = rowm * (CHUNK * 4) + nl_ * 4;                                  \
    f32x4 e0_ = *(const f32x4*)(eb_ + (by_ ^ rsw));                                \
    f32x4 e1_ = *(const f32x4*)(eb_ + ((by_ + 16) ^ rsw));                         \
    short8 ed_ = *(const short8*)(&eds[h * N_TOK + (cc) * CHUNK + nl_]);           \
    float p0_ = e0_[0] * bf2f((unsigned short)ed_[0]);                             \
    float p1_ = e0_[1] * bf2f((unsigned short)ed_[1]);                             \
    float p2_ = e0_[2] * bf2f((unsigned short)ed_[2]);                             \
    float p3_ = e0_[3] * bf2f((unsigned short)ed_[3]);                             \
    float p4_ = e1_[0] * bf2f((unsigned short)ed_[4]);                             \
    float p5_ = e1_[1] * bf2f((unsigned short)ed_[5]);                             \
    float p6_ = e1_[2] * bf2f((unsigned short)ed_[6]);                             \
    float p7_ = e1_[3] * bf2f((unsigned short)ed_[7]);                             \
    dsum += ((p0_ + p1_) + (p2_ + p3_)) + ((p4_ + p5_) + (p6_ + p7_));             \
    Frag af_; uint4v u_;                                                           \
    u_[0] = __builtin_amdgcn_perm(__float_as_uint(p1_), __float_as_uint(p0_), 0x07060302u); \
    u_[1] = __builtin_amdgcn_perm(__float_as_uint(p3_), __float_as_uint(p2_), 0x07060302u); \
    u_[2] = __builtin_amdgcn_perm(__float_as_uint(p5_), __float_as_uint(p4_), 0x07060302u); \
    u_[3] = __builtin_amdgcn_perm(__float_as_uint(p7_), __float_as_uint(p6_), 0x07060302u); \
    af_.u = u_;                                                                    \
    acc = __builtin_amdgcn_mfma_f32_16x16x32_bf16(af_.v, fr.v, acc, 0, 0, 0);      \
  } while (0)

// Steady-state per-wave VMEM queue at the vmcnt(9): [S(c+1), B(c)x4, S(c+2), B(c+1)x4]
#define ITER(cc, C0, C1, C2, C3, N0, N1, N2, N3) do {                              \
    const int cn_ = ((cc) + 1 < NCH) ? (cc) + 1 : NCH - 1;                         \
    const int cs_ = ((cc) + 3 < NCH) ? (cc) + 3 : NCH - 1;                         \
    LOADB(N0, cn_, 0); LOADB(N1, cn_, 1); LOADB(N2, cn_, 2); LOADB(N3, cn_, 3);    \
    asm volatile("s_waitcnt vmcnt(9)" ::: "memory");   /* drain S(c+1) */          \
    __builtin_amdgcn_sched_barrier(0);                                             \
    EXPP(((cc) + 1) & 3);                                                          \
    asm volatile("s_waitcnt lgkmcnt(0)" ::: "memory");                             \
    __builtin_amdgcn_sched_barrier(0);                                             \
    __builtin_amdgcn_s_barrier();                                                  \
    asm volatile("s_waitcnt vmcnt(5)" ::: "memory");   /* drain B(c)x4 */          \
    __builtin_amdgcn_sched_barrier(0);                                             \
    STAGE(((cc) + 3) & 3, cs_);                                                    \
    MSTEP(C0, cc, 0); MSTEP(C1, cc, 1); MSTEP(C2, cc, 2); MSTEP(C3, cc, 3);        \
  } while (0)

  // prologue
  STAGE(0, 0);
  asm volatile("s_waitcnt vmcnt(0)" ::: "memory");
  __builtin_amdgcn_sched_barrier(0);
  EXPP(0);
  asm volatile("s_waitcnt lgkmcnt(0)" ::: "memory");
  __builtin_amdgcn_sched_barrier(0);
  __builtin_amdgcn_s_barrier();
  STAGE(1, 1);
  LOADB(fa0, 0, 0); LOADB(fa1, 0, 1); LOADB(fa2, 0, 2); LOADB(fa3, 0, 3);
  STAGE(2, 2);

#pragma unroll 1
  for (int c = 0; c < NCH; c += 2) {
    ITER(c,     fa0, fa1, fa2, fa3, fb0, fb1, fb2, fb3);
    ITER(c + 1, fb0, fb1, fb2, fb3, fa0, fa1, fa2, fa3);
  }

  // epilogue: rowsum reduce (k-groups live in lanes l, l^16, l^32, l^48)
  float den = dsum;
  den += __shfl_xor(den, 16);
  den += __shfl_xor(den, 32);
#pragma unroll
  for (int r = 0; r < 4; ++r) {
    const int orow = (lane >> 4) * 4 + r;          // C/D: row=(l>>4)*4+reg, col=l&15
    const float d = __shfl(den, orow);             // lanes 0..15 hold den[row]
    float o = acc[r] / d;
    o = o > 0.f ? o : 0.f;
    out[(size_t)(b0 + orow) * OUTW + h * NF + f0 + rowm] = o;
  }
#undef STAGE
#undef LOADB
#undef EXPP
#undef MSTEP
#undef ITER
}

extern "C" void kernel_launch(void* const* d_in, const int* in_sizes, int n_in,
                              void* d_out, int out_size, void* d_ws, size_t ws_size,
                              hipStream_t stream) {
  // inputs: 0=X(unused) 1=G 2=A 3=W 4=b 5=a_src(unused) 6=a_dst 7=att_b(unused)
  const float* G     = (const float*)d_in[1];
  const float* A     = (const float*)d_in[2];
  const float* W     = (const float*)d_in[3];
  const float* bias  = (const float*)d_in[4];
  const float* a_dst = (const float*)d_in[6];

  unsigned short* ED  = (unsigned short*)d_ws;                    // 32 KB
  unsigned short* WGT = (unsigned short*)((char*)d_ws + 32768);   // 1 MB
  float* outp = (float*)d_out;

  prep_kernel<<<N_TOK / NT, 128, 0, stream>>>(G, W, bias, a_dst, ED, WGT);
  attn_kernel<<<4096 / BT, 512, 0, stream>>>(A, ED, WGT, outp);
}

// Round 3
// 50.941 us; speedup vs baseline: 1.3062x; 1.3062x over previous
//
#include <hip/hip_runtime.h>
#include <stdint.h>

#define N_TOK 4096
#define D_IN  64
#define NF    32
#define NH    4
#define OUTW  (NH * NF)        // 128
#define CHUNK 128
#define BT    16
#define NT    8

typedef float        f32x4  __attribute__((ext_vector_type(4)));
typedef unsigned int uint4v __attribute__((ext_vector_type(4)));
typedef __bf16       bf16x8 __attribute__((ext_vector_type(8)));

union Frag { uint4v u; bf16x8 v; };

static __device__ __forceinline__ unsigned short f2bf_rne(float x) {
  unsigned u = __float_as_uint(x);
  u += 0x7fffu + ((u >> 16) & 1u);
  return (unsigned short)(u >> 16);
}
static __device__ __forceinline__ float bflo(unsigned x) {
  return __uint_as_float(x << 16);
}
static __device__ __forceinline__ float bfhi(unsigned x) {
  return __uint_as_float(x & 0xffff0000u);
}

// ---------- Kernel 1: WG2^T = (E*WG) bf16 [h][f][n], ED4 bf16 [n][h] ----------
__global__ __launch_bounds__(128) void prep_kernel(
    const float* __restrict__ G, const float* __restrict__ W,
    const float* __restrict__ bias, const float* __restrict__ a_dst,
    unsigned short* __restrict__ ED4, unsigned short* __restrict__ WG2T) {
  __shared__ float gs[NT * D_IN];  // 8 G rows, 2 KB
  const int tid = threadIdx.x;
  const int n0  = blockIdx.x * NT;
  {
    const float4* src = (const float4*)(G + (size_t)n0 * D_IN);
    float4* dst = (float4*)gs;
    dst[tid] = src[tid];
  }
  __syncthreads();
  const int h = tid >> 5, f = tid & 31;
  float acc[NT];
  const float bb = bias[h * NF + f];
#pragma unroll
  for (int k = 0; k < NT; ++k) acc[k] = bb;
#pragma unroll
  for (int i = 0; i < D_IN; ++i) {
    const float wv = W[(h * D_IN + i) * NF + f];
#pragma unroll
    for (int k = 0; k < NT; ++k) acc[k] = fmaf(gs[k * D_IN + i], wv, acc[k]);
  }
  const float ad = a_dst[h * NF + f];
  float ev[NT];
#pragma unroll
  for (int k = 0; k < NT; ++k) {
    float s = acc[k] * ad;
    s += __shfl_xor(s, 1);  s += __shfl_xor(s, 2);  s += __shfl_xor(s, 4);
    s += __shfl_xor(s, 8);  s += __shfl_xor(s, 16);
    ev[k] = __expf(s);
  }
  union { uint4 u4; unsigned short us[8]; } pk;
#pragma unroll
  for (int k = 0; k < NT; ++k) pk.us[k] = f2bf_rne(acc[k] * ev[k]);
  *(uint4*)&WG2T[(size_t)(h * NF + f) * N_TOK + n0] = pk.u4;
  if (f == 0) {
#pragma unroll
    for (int k = 0; k < NT; ++k) ED4[(size_t)(n0 + k) * NH + h] = f2bf_rne(ev[k]);
  }
}

// ---------- Kernel 2: masked-softmax-PV (optionally split over n) ----------
// grid = 256*NS blocks, 512 thr (8 waves: h = wv>>1, f-half = (wv&1)*16).
// SPLIT=1: write partial numerator/denominator to op/dp. SPLIT=0: direct out.
template <int SPLIT>
__global__ __launch_bounds__(512) void attn_kernel(
    const float* __restrict__ A, const unsigned short* __restrict__ ED4,
    const unsigned short* __restrict__ WG2T, float* __restrict__ op,
    float* __restrict__ dp, float* __restrict__ out, int NC) {
  extern __shared__ char smem[];
  char* ebase  = smem;                                   // exp ring, 3 x 4096 B
  char* edsB   = smem + 12288;                           // ED4 slice, NC*1024 B
  float* denLds = (float*)(smem + 12288 + (size_t)NC * 1024);  // 64 floats

  const int tid  = threadIdx.x;
  const int lane = tid & 63;
  const int wv   = tid >> 6;
  const int h    = wv >> 1;
  const int f0   = (wv & 1) * 16;
  const int bid  = blockIdx.x;
  const int btile = bid & 255;
  const int s     = bid >> 8;
  const int b0    = btile * BT;
  const int c0    = s * NC;
  const int clast = c0 + NC - 1;

  // exp-pass coords: thread = (row srow, 4-col window ncol)
  const int srow = tid >> 5, ncol = tid & 31;
  const float* abase = A + (size_t)(b0 + srow) * N_TOK + ncol * 4;

  // MFMA frag coords
  const int rowm = lane & 15, g = lane >> 4;
  const unsigned short* wbase =
      WG2T + (size_t)(h * NF + f0 + rowm) * N_TOK + g * 8;

  // preload this split's ED4 slice into LDS
  {
    const uint4* esrc = (const uint4*)(ED4 + (size_t)c0 * 512);
    uint4* edst = (uint4*)edsB;
    const int tot = NC * 64;
    for (int i = tid; i < tot; i += 512) edst[i] = esrc[i];
  }
  __syncthreads();

  // swizzled LDS offsets (16B-granule XOR with row; same permutation both sides)
  const int wroff = srow * 256 + ((((ncol >> 1) ^ srow) & 15) << 4) + ((ncol & 1) << 3);
  const int rdo0 = rowm * 256 + (((0  + g) ^ rowm) << 4);
  const int rdo1 = rowm * 256 + (((4  + g) ^ rowm) << 4);
  const int rdo2 = rowm * 256 + (((8  + g) ^ rowm) << 4);
  const int rdo3 = rowm * 256 + (((12 + g) ^ rowm) << 4);

  f32x4 acc  = {0.f, 0.f, 0.f, 0.f};
  f32x4 dsum = {0.f, 0.f, 0.f, 0.f};
  f32x4 a0, a1;
  Frag fb0, fb1, fb2, fb3;

#define LOADA(dst, cc)                                                         \
  asm volatile("global_load_dwordx4 %0, %1, off"                              \
               : "=v"(dst) : "v"(abase + (size_t)(cc) * CHUNK) : "memory")
#define LOADB(fr, cc, ss)                                                      \
  asm volatile("global_load_dwordx4 %0, %1, off"                              \
               : "=v"(fr.u)                                                    \
               : "v"(wbase + (size_t)(cc) * CHUNK + (ss) * 32) : "memory")

// exp + (guarded) denominator-FMA vs LDS E-table + bf16 pack + swizzled ds_write
#define EXPP(AV, cc, mw) do {                                                  \
    float x0 = __expf(-AV[0]), x1 = __expf(-AV[1]);                            \
    float x2 = __expf(-AV[2]), x3 = __expf(-AV[3]);                            \
    if ((cc) <= clast) {                                                       \
      const char* ep_ = edsB + (size_t)((cc) - c0) * 1024 + ncol * 32;         \
      uint4v ea_ = *(const uint4v*)ep_;                                        \
      uint4v eb_ = *(const uint4v*)(ep_ + 16);                                 \
      dsum[0] = fmaf(x0, bflo(ea_[0]), dsum[0]);                               \
      dsum[1] = fmaf(x0, bfhi(ea_[0]), dsum[1]);                               \
      dsum[2] = fmaf(x0, bflo(ea_[1]), dsum[2]);                               \
      dsum[3] = fmaf(x0, bfhi(ea_[1]), dsum[3]);                               \
      dsum[0] = fmaf(x1, bflo(ea_[2]), dsum[0]);                               \
      dsum[1] = fmaf(x1, bfhi(ea_[2]), dsum[1]);                               \
      dsum[2] = fmaf(x1, bflo(ea_[3]), dsum[2]);                               \
      dsum[3] = fmaf(x1, bfhi(ea_[3]), dsum[3]);                               \
      dsum[0] = fmaf(x2, bflo(eb_[0]), dsum[0]);                               \
      dsum[1] = fmaf(x2, bfhi(eb_[0]), dsum[1]);                               \
      dsum[2] = fmaf(x2, bflo(eb_[1]), dsum[2]);                               \
      dsum[3] = fmaf(x2, bfhi(eb_[1]), dsum[3]);                               \
      dsum[0] = fmaf(x3, bflo(eb_[2]), dsum[0]);                               \
      dsum[1] = fmaf(x3, bfhi(eb_[2]), dsum[1]);                               \
      dsum[2] = fmaf(x3, bflo(eb_[3]), dsum[2]);                               \
      dsum[3] = fmaf(x3, bfhi(eb_[3]), dsum[3]);                               \
    }                                                                          \
    unsigned p0_ = __builtin_amdgcn_perm(__float_as_uint(x1),                  \
                                         __float_as_uint(x0), 0x07060302u);    \
    unsigned p1_ = __builtin_amdgcn_perm(__float_as_uint(x3),                  \
                                         __float_as_uint(x2), 0x07060302u);    \
    uint2 w_; w_.x = p0_; w_.y = p1_;                                          \
    *(uint2*)(ebase + (mw) * 4096 + wroff) = w_;                               \
  } while (0)

#define MSTEP(fr, rdo) do {                                                    \
    Frag af_;                                                                  \
    af_.v = *(const bf16x8*)(ebase + mR * 4096 + (rdo));                       \
    acc = __builtin_amdgcn_mfma_f32_16x16x32_bf16(af_.v, fr.v, acc, 0, 0, 0);  \
  } while (0)

// per-wave VMEM queue at entry: [A(c+1)]; issue B(c)x4 then A(c+2);
// vmcnt(5) -> A(c+1) done; vmcnt(1) -> B(c) done, A(c+2) stays in flight.
#define ITER(cc, AV, AV2) do {                                                 \
    LOADB(fb0, cc, 0); LOADB(fb1, cc, 1); LOADB(fb2, cc, 2); LOADB(fb3, cc, 3);\
    { const int ca_ = ((cc) + 2 <= clast) ? (cc) + 2 : clast;                  \
      LOADA(AV2, ca_); }                                                       \
    asm volatile("s_waitcnt vmcnt(5)" ::: "memory");                           \
    __builtin_amdgcn_sched_barrier(0);                                         \
    EXPP(AV, (cc) + 1, mW);                                                    \
    asm volatile("s_waitcnt lgkmcnt(0)" ::: "memory");                         \
    __builtin_amdgcn_sched_barrier(0);                                         \
    __builtin_amdgcn_s_barrier();                                              \
    asm volatile("s_waitcnt vmcnt(1)" ::: "memory");                           \
    __builtin_amdgcn_sched_barrier(0);                                         \
    MSTEP(fb0, rdo0); MSTEP(fb1, rdo1); MSTEP(fb2, rdo2); MSTEP(fb3, rdo3);    \
    mR = mW; mW = (mW + 1 == 3) ? 0 : mW + 1;                                  \
  } while (0)

  int mR = 0, mW = 1;

  // prologue: prefetch chunks c0, c0+1; exp chunk c0 into ring[mR]
  LOADA(a0, c0);
  LOADA(a1, c0 + 1);
  asm volatile("s_waitcnt vmcnt(1)" ::: "memory");
  __builtin_amdgcn_sched_barrier(0);
  EXPP(a0, c0, mR);

#pragma unroll 1
  for (int i = 0; i < NC; i += 2) {
    ITER(c0 + i,     a1, a0);
    ITER(c0 + i + 1, a0, a1);
  }

  // CRITICAL: drain all in-flight asm loads before the epilogue can reuse
  // their (now dead) destination registers.
  asm volatile("s_waitcnt vmcnt(0)" ::: "memory");
  __builtin_amdgcn_sched_barrier(0);

  // denominator: reduce over the 32 threads sharing a row
#pragma unroll
  for (int m = 1; m <= 16; m <<= 1) {
    dsum[0] += __shfl_xor(dsum[0], m);
    dsum[1] += __shfl_xor(dsum[1], m);
    dsum[2] += __shfl_xor(dsum[2], m);
    dsum[3] += __shfl_xor(dsum[3], m);
  }

  if (SPLIT) {
    if (ncol == 0) {
      float4 dv; dv.x = dsum[0]; dv.y = dsum[1]; dv.z = dsum[2]; dv.w = dsum[3];
      *(float4*)&dp[((size_t)s * N_TOK + b0 + srow) * NH] = dv;
    }
    // partial numerator: C/D row=(lane>>4)*4+r, col=lane&15
    float* obase = op + (size_t)s * (N_TOK * OUTW) + (size_t)b0 * OUTW
                 + h * NF + f0 + rowm;
#pragma unroll
    for (int r = 0; r < 4; ++r) obase[(size_t)(g * 4 + r) * OUTW] = acc[r];
  } else {
    if (ncol == 0) {
      float4 dv; dv.x = dsum[0]; dv.y = dsum[1]; dv.z = dsum[2]; dv.w = dsum[3];
      *(float4*)&denLds[srow * 4] = dv;
    }
    __syncthreads();
#pragma unroll
    for (int r = 0; r < 4; ++r) {
      const int orow = g * 4 + r;
      const float den = denLds[orow * 4 + h];
      float o = acc[r] / den;
      out[(size_t)(b0 + orow) * OUTW + h * NF + f0 + rowm] = o > 0.f ? o : 0.f;
    }
  }
#undef LOADA
#undef LOADB
#undef EXPP
#undef MSTEP
#undef ITER
}

// ---------- Kernel 3: combine splits, divide, relu ----------
__global__ __launch_bounds__(256) void comb_kernel(
    const float* __restrict__ op, const float* __restrict__ dp,
    float* __restrict__ out, int NS) {
  const int idx4 = blockIdx.x * 256 + threadIdx.x;  // 131072 float4s
  const int eb = idx4 >> 5;
  const int h  = ((idx4 << 2) & 127) >> 5;
  float4 o; o.x = 0.f; o.y = 0.f; o.z = 0.f; o.w = 0.f;
  float d = 0.f;
  for (int s2 = 0; s2 < NS; ++s2) {
    float4 v = *(const float4*)(op + (size_t)s2 * (N_TOK * OUTW) + (size_t)idx4 * 4);
    o.x += v.x; o.y += v.y; o.z += v.z; o.w += v.w;
    d += dp[((size_t)s2 * N_TOK + eb) * NH + h];
  }
  const float r = 1.f / d;
  float4 res;
  res.x = fmaxf(o.x * r, 0.f);
  res.y = fmaxf(o.y * r, 0.f);
  res.z = fmaxf(o.z * r, 0.f);
  res.w = fmaxf(o.w * r, 0.f);
  *(float4*)(out + (size_t)idx4 * 4) = res;
}

extern "C" void kernel_launch(void* const* d_in, const int* in_sizes, int n_in,
                              void* d_out, int out_size, void* d_ws, size_t ws_size,
                              hipStream_t stream) {
  // inputs: 0=X(unused) 1=G 2=A 3=W 4=b 5=a_src(unused) 6=a_dst 7=att_b(unused)
  const float* G     = (const float*)d_in[1];
  const float* A     = (const float*)d_in[2];
  const float* W     = (const float*)d_in[3];
  const float* bias  = (const float*)d_in[4];
  const float* a_dst = (const float*)d_in[6];

  char* ws = (char*)d_ws;
  unsigned short* WG2T = (unsigned short*)ws;               // 1 MB
  unsigned short* ED4  = (unsigned short*)(ws + 1048576);   // 32 KB
  const size_t base = 1048576 + 32768;
  const size_t per_split = (size_t)N_TOK * OUTW * 4 + (size_t)N_TOK * NH * 4;  // 2 MB + 64 KB

  int NS = 1;
  if (ws_size >= base + 4 * per_split) NS = 4;
  else if (ws_size >= base + 2 * per_split) NS = 2;

  const int NC = 32 / NS;
  float* op = (float*)(ws + base);
  float* dp = (float*)(ws + base + (size_t)NS * N_TOK * OUTW * 4);
  float* outp = (float*)d_out;
  const size_t shmem = 12288 + (size_t)NC * 1024 + 256;

  prep_kernel<<<N_TOK / NT, 128, 0, stream>>>(G, W, bias, a_dst, ED4, WG2T);
  if (NS > 1) {
    attn_kernel<1><<<256 * NS, 512, shmem, stream>>>(A, ED4, WG2T, op, dp, nullptr, NC);
    comb_kernel<<<(N_TOK * OUTW / 4) / 256, 256, 0, stream>>>(op, dp, outp, NS);
  } else {
    attn_kernel<0><<<256, 512, shmem, stream>>>(A, ED4, WG2T, nullptr, nullptr, outp, NC);
  }
}